// Round 2
// baseline (420.431 us; speedup 1.0000x reference)
//
#include <hip/hip_runtime.h>
#include <math.h>

// Router: logits = x@Wg ; softmax ; top-2 ; renormalized combine.
// T=65536, D=1024, E=64. Out flat fp32: [combine 2T][idx-as-float 2T][probs 64T].
//
// R8 = R7 (split-bf16 MFMA GEMM) + deterministic flag-and-repair for top-k ties.
//   R7 verified on HW: combine passed (GEMM/layout/swizzle correct); idx failed on
//   13 tokens = near-tie flips from the ~4e-6 split-bf16 logit noise (predicted).
//   Fix: epilogue selects top-2 on RAW logits and tracks the 3rd-largest value.
//   If gap(1,2) or gap(2,3) < MARGIN (1e-3, ~20x the 5-sigma error bound), the
//   token id is appended to a workspace list; repair_kernel recomputes those
//   tokens' logits exactly (fp64 accumulate -> fp32), redoes softmax/top-2, and
//   overwrites their combine/idx/probs rows. Approx ordering == exact ordering
//   is guaranteed outside the margin (gap >= 2*|err|max). ~900 repairs expected.
//   Counter zeroed in wprep (same-stream order) -> graph-replay idempotent.

#define D_DIM 1024
#define E_DIM 64
#define TM    128              // tokens per block (4 waves x 32 tokens)
#define KC    64               // K per LDS chunk
#define NCH   (D_DIM / KC)     // 16
#define TPB   256
#define MARGIN 1e-3f
#define WT_U4  16384           // uint4 granules in W planes (256 KB)

typedef float f32x4 __attribute__((ext_vector_type(4)));
typedef short s16x8 __attribute__((ext_vector_type(8)));

__device__ __forceinline__ unsigned bf16hi_rne(unsigned u) {
  // round-to-nearest-even to bf16; returns f32 bit pattern with low 16 bits zero
  return (u + 0x7FFFu + ((u >> 16) & 1u)) & 0xFFFF0000u;
}

// ---- W prep: Wg [1024][64] f32 -> wt bf16, layout [plane(hi,lo)][ch][e][g][j]
// (uint4 granules of 8 bf16). Granule g of row e holds source k-granule g^(e&7)
// of the chunk (XOR bank swizzle, G4). Also zeroes the repair counter.
__global__ void wprep_kernel(const float* __restrict__ Wg, uint4* __restrict__ w4,
                             unsigned* __restrict__ ctr) {
  const int gi = blockIdx.x * blockDim.x + threadIdx.x;   // 0..8191
  if (gi == 0) ctr[0] = 0u;
  const int ch = gi >> 9;
  const int e  = (gi >> 3) & 63;
  const int g  = gi & 7;
  const int k0 = ch * KC + (g ^ (e & 7)) * 8;
  unsigned hp[4], lp[4];
#pragma unroll
  for (int jj = 0; jj < 4; ++jj) {
    const float w0 = Wg[(k0 + 2 * jj    ) * E_DIM + e];
    const float w1 = Wg[(k0 + 2 * jj + 1) * E_DIM + e];
    const unsigned h0 = bf16hi_rne(__float_as_uint(w0));
    const unsigned h1 = bf16hi_rne(__float_as_uint(w1));
    const float l0 = w0 - __uint_as_float(h0);   // exact in fp32
    const float l1 = w1 - __uint_as_float(h1);
    hp[jj] = h1 | (h0 >> 16);
    lp[jj] = bf16hi_rne(__float_as_uint(l1)) | (bf16hi_rne(__float_as_uint(l0)) >> 16);
  }
  w4[gi]         = make_uint4(hp[0], hp[1], hp[2], hp[3]);   // hi plane
  w4[8192 + gi]  = make_uint4(lp[0], lp[1], lp[2], lp[3]);   // lo plane
}

struct Frag2 { s16x8 hi, lo; };

// 8 consecutive fp32 (k-run) -> hi/lo bf16x8 fragments, element j = k-order.
__device__ __forceinline__ Frag2 cvt8(const float4 a, const float4 b) {
  const float f[8] = {a.x, a.y, a.z, a.w, b.x, b.y, b.z, b.w};
  unsigned h[8], l[8];
#pragma unroll
  for (int i = 0; i < 8; ++i) {
    const unsigned hb = bf16hi_rne(__float_as_uint(f[i]));
    const float lf = f[i] - __uint_as_float(hb);
    h[i] = hb;
    l[i] = bf16hi_rne(__float_as_uint(lf));
  }
  union { uint4 u; s16x8 v; } H, L;
  H.u = make_uint4(h[1] | (h[0] >> 16), h[3] | (h[2] >> 16),
                   h[5] | (h[4] >> 16), h[7] | (h[6] >> 16));
  L.u = make_uint4(l[1] | (l[0] >> 16), l[3] | (l[2] >> 16),
                   l[5] | (l[4] >> 16), l[7] | (l[6] >> 16));
  Frag2 r; r.hi = H.v; r.lo = L.v; return r;
}

__global__ __launch_bounds__(TPB, 2) void router_mfma(
    const float* __restrict__ x, const uint4* __restrict__ wt,
    float* __restrict__ out, unsigned* __restrict__ ctr,
    unsigned* __restrict__ list, int rcap, int T)
{
  // [buf][plane*512 + e*8 + g] uint4 granules; 32 KB total
  __shared__ uint4 sw[2][1024];

  const int tid   = threadIdx.x;
  const int wid   = tid >> 6;
  const int lane  = tid & 63;
  const int c     = lane & 15;     // token col within 16-tile / expert row within A-tile
  const int q     = lane >> 4;     // quarter -> k-group
  const int twave = blockIdx.x * TM + wid * 32;

  f32x4 acc[4][2];                 // [etile][ttile]
#pragma unroll
  for (int et = 0; et < 4; ++et)
#pragma unroll
    for (int tt = 0; tt < 2; ++tt)
      acc[et][tt] = (f32x4){0.f, 0.f, 0.f, 0.f};

  const float* xb0 = x + (size_t)(twave + c) * D_DIM + q * 8;
  const float* xb1 = xb0 + (size_t)16 * D_DIM;

  uint4  wr[4];
  float4 xr[8];

  // ---- prologue: W ch0 -> LDS buf0; x ch0 -> regs; W ch1 -> regs
#pragma unroll
  for (int i = 0; i < 4; ++i) wr[i] = wt[(i >> 1) * 8192 + (i & 1) * 256 + tid];
#pragma unroll
  for (int i = 0; i < 4; ++i) sw[0][(i >> 1) * 512 + (i & 1) * 256 + tid] = wr[i];
#pragma unroll
  for (int v = 0; v < 8; ++v) {
    const int tt = v >> 2, s = (v >> 1) & 1, h = v & 1;
    const float* b = (tt ? xb1 : xb0);
    xr[v] = *(const float4*)(b + s * 32 + h * 4);
  }
#pragma unroll
  for (int i = 0; i < 4; ++i) wr[i] = wt[(i >> 1) * 8192 + 512 + (i & 1) * 256 + tid];
  __syncthreads();

  const int row0 = c * 64;                 // ushort offset of row c (etile adds 1024)
  const int g0 = ((0 + q) ^ (c & 7)) * 8;  // swizzled granule, s=0
  const int g1 = ((4 + q) ^ (c & 7)) * 8;  // swizzled granule, s=1

  for (int ch = 0; ch < NCH; ++ch) {
    const int cur = ch & 1;
    if (ch + 1 < NCH) {                    // W regs(ch+1) -> other buffer
#pragma unroll
      for (int i = 0; i < 4; ++i)
        sw[cur ^ 1][(i >> 1) * 512 + (i & 1) * 256 + tid] = wr[i];
    }
    if (ch + 2 < NCH) {                    // prefetch W ch+2
#pragma unroll
      for (int i = 0; i < 4; ++i)
        wr[i] = wt[(i >> 1) * 8192 + (ch + 2) * 512 + (i & 1) * 256 + tid];
    }

    // convert this chunk's x (loaded last iter) -> bf16 hi/lo B-fragments
    Frag2 bx[2][2];                        // [ttile][s]
#pragma unroll
    for (int tt = 0; tt < 2; ++tt)
#pragma unroll
      for (int s = 0; s < 2; ++s)
        bx[tt][s] = cvt8(xr[tt * 4 + s * 2 + 0], xr[tt * 4 + s * 2 + 1]);

    // prefetch next chunk's x (HBM latency hides under a full chunk of compute)
    if (ch + 1 < NCH) {
#pragma unroll
      for (int v = 0; v < 8; ++v) {
        const int tt = v >> 2, s = (v >> 1) & 1, h = v & 1;
        const float* b = (tt ? xb1 : xb0);
        xr[v] = *(const float4*)(b + (ch + 1) * KC + s * 32 + h * 4);
      }
    }

    const ushort* bufh = (const ushort*)&sw[cur][0];
    const ushort* bufl = bufh + 4096;      // lo plane
#pragma unroll
    for (int s = 0; s < 2; ++s) {
      const int go = s ? g1 : g0;
      s16x8 ah[4], al[4];
#pragma unroll
      for (int et = 0; et < 4; ++et) {
        ah[et] = *(const s16x8*)(bufh + et * 1024 + row0 + go);
        al[et] = *(const s16x8*)(bufl + et * 1024 + row0 + go);
      }
#pragma unroll
      for (int et = 0; et < 4; ++et)
#pragma unroll
        for (int tt = 0; tt < 2; ++tt) {
          f32x4 a = acc[et][tt];
          a = __builtin_amdgcn_mfma_f32_16x16x32_bf16(ah[et], bx[tt][s].hi, a, 0, 0, 0);
          a = __builtin_amdgcn_mfma_f32_16x16x32_bf16(ah[et], bx[tt][s].lo, a, 0, 0, 0);
          a = __builtin_amdgcn_mfma_f32_16x16x32_bf16(al[et], bx[tt][s].hi, a, 0, 0, 0);
          acc[et][tt] = a;
        }
    }
    __syncthreads();
  }

  // ---- epilogue: token t lives in lanes {c, c+16, c+32, c+48}; 16 logits/lane:
  // expert = et*16 + q*4 + r  (C/D layout: col=lane&15, row=(lane>>4)*4+reg)
  const size_t Ts = (size_t)T;
  float* const comb = out;
  float* const idxo = out + 2 * Ts;
  float* const prob = out + 4 * Ts;

#pragma unroll
  for (int tt = 0; tt < 2; ++tt) {
    const int tok = twave + tt * 16 + c;
    float v[16];
#pragma unroll
    for (int et = 0; et < 4; ++et)
#pragma unroll
      for (int r = 0; r < 4; ++r) v[et * 4 + r] = acc[et][tt][r];

    // per-lane top-3 on raw logits (indices for top-2; ties -> lower index)
    float v1 = v[0], v2 = -INFINITY, v3 = -INFINITY;
    int   i1 = q * 4, i2 = 0;
#pragma unroll
    for (int et = 0; et < 4; ++et)
#pragma unroll
      for (int r = 0; r < 4; ++r) {
        if (et == 0 && r == 0) continue;
        const float p  = v[et * 4 + r];
        const int   ei = et * 16 + q * 4 + r;
        if (p > v1)      { v3 = v2; v2 = v1; i2 = i1; v1 = p; i1 = ei; }
        else if (p > v2) { v3 = v2; v2 = p;  i2 = ei; }
        else if (p > v3) { v3 = p; }
      }
    // merge top-3 across the 4 q-lanes (xor 16, 32); stable, symmetric
#pragma unroll
    for (int d = 16; d <= 32; d <<= 1) {
      const float ov1 = __shfl_xor(v1, d); const int oi1 = __shfl_xor(i1, d);
      const float ov2 = __shfl_xor(v2, d); const int oi2 = __shfl_xor(i2, d);
      const float ov3 = __shfl_xor(v3, d);
      const bool  ob1 = (ov1 > v1) || (ov1 == v1 && oi1 < i1);
      const float w1v = ob1 ? ov1 : v1;  const int w1i = ob1 ? oi1 : i1;
      const float l1v = ob1 ? v1  : ov1; const int l1i = ob1 ? i1  : oi1;
      const float w2v = ob1 ? ov2 : v2;  const int w2i = ob1 ? oi2 : i2;
      const float ls2 = ob1 ? v2  : ov2;                 // loser-side 2nd (value only)
      const float ws3 = ob1 ? ov3 : v3;                  // winner-side 3rd (value only)
      const bool  b2  = (l1v > w2v) || (l1v == w2v && l1i < w2i);
      const float a2v = b2 ? l1v : w2v; const int a2i = b2 ? l1i : w2i;
      const float a3v = b2 ? fmaxf(w2v, ls2) : fmaxf(l1v, ws3);
      v1 = w1v; i1 = w1i; v2 = a2v; i2 = a2i; v3 = a3v;
    }

    // softmax: v1 is the exact max logit across all 64 experts
    float s = 0.f;
#pragma unroll
    for (int i = 0; i < 16; ++i) { v[i] = __expf(v[i] - v1); s += v[i]; }
    s += __shfl_xor(s, 16);
    s += __shfl_xor(s, 32);
    const float inv = 1.f / s;

#pragma unroll
    for (int et = 0; et < 4; ++et)
      *(float4*)&prob[(size_t)tok * E_DIM + et * 16 + q * 4] =
          make_float4(v[et * 4 + 0] * inv, v[et * 4 + 1] * inv,
                      v[et * 4 + 2] * inv, v[et * 4 + 3] * inv);

    if (q == 0) {
      if ((v1 - v2 < MARGIN) || (v2 - v3 < MARGIN)) {   // near-tie: queue exact repair
        const unsigned slot = atomicAdd(ctr, 1u);
        if ((int)slot < rcap) list[slot] = (unsigned)tok;
      }
      const float c1 = 1.f / (1.f + __expf(v2 - v1));   // == p1/(p1+p2)
      *(float2*)&comb[2 * (size_t)tok] = make_float2(c1, 1.f - c1);
      *(float2*)&idxo[2 * (size_t)tok] = make_float2((float)i1, (float)i2);
    }
  }
}

// ---- exact repair: recompute flagged tokens' logits in fp64, overwrite outputs.
__global__ __launch_bounds__(256) void repair_kernel(
    const float* __restrict__ x, const float* __restrict__ Wg,
    float* __restrict__ out, const unsigned* __restrict__ ctr,
    const unsigned* __restrict__ list, int rcap, int T)
{
  __shared__ double part[4][E_DIM];
  const int tid = threadIdx.x;
  const int e   = tid & 63;
  const int s   = tid >> 6;
  const unsigned total = ctr[0];
  const unsigned n = total < (unsigned)rcap ? total : (unsigned)rcap;

  for (unsigned j = blockIdx.x; j < n; j += gridDim.x) {
    const int t = (int)list[j];
    const float* xr = x  + (size_t)t * D_DIM + s * 256;
    const float* wr = Wg + (size_t)(s * 256) * E_DIM + e;
    double a = 0.0;
#pragma unroll 8
    for (int d = 0; d < 256; ++d)
      a += (double)xr[d] * (double)wr[(size_t)d * E_DIM];
    part[s][e] = a;
    __syncthreads();
    if (tid < 64) {
      const float l = (float)(part[0][e] + part[1][e] + part[2][e] + part[3][e]);
      // wave-wide softmax over 64 experts
      float m = l;
#pragma unroll
      for (int d2 = 1; d2 < 64; d2 <<= 1) m = fmaxf(m, __shfl_xor(m, d2));
      const float p = expf(l - m);
      float ss = p;
#pragma unroll
      for (int d2 = 1; d2 < 64; d2 <<= 1) ss += __shfl_xor(ss, d2);
      out[4 * (size_t)T + (size_t)t * E_DIM + e] = p / ss;
      // wave-wide stable top-2 (ties -> lower index)
      float v1 = l, v2 = -INFINITY; int i1 = e, i2 = 0;
#pragma unroll
      for (int d2 = 1; d2 < 64; d2 <<= 1) {
        const float ov1 = __shfl_xor(v1, d2); const int oi1 = __shfl_xor(i1, d2);
        const float ov2 = __shfl_xor(v2, d2); const int oi2 = __shfl_xor(i2, d2);
        const bool  ob1 = (ov1 > v1) || (ov1 == v1 && oi1 < i1);
        const float w1v = ob1 ? ov1 : v1;  const int w1i = ob1 ? oi1 : i1;
        const float l1v = ob1 ? v1  : ov1; const int l1i = ob1 ? i1  : oi1;
        const float w2v = ob1 ? ov2 : v2;  const int w2i = ob1 ? oi2 : i2;
        const bool  b2  = (l1v > w2v) || (l1v == w2v && l1i < w2i);
        v1 = w1v; i1 = w1i;
        v2 = b2 ? l1v : w2v; i2 = b2 ? l1i : w2i;
      }
      if (e == 0) {
        const float c1 = 1.f / (1.f + expf(v2 - v1));
        out[2 * (size_t)t]     = c1;
        out[2 * (size_t)t + 1] = 1.f - c1;
        out[2 * (size_t)T + 2 * (size_t)t]     = (float)i1;
        out[2 * (size_t)T + 2 * (size_t)t + 1] = (float)i2;
      }
    }
    __syncthreads();
  }
}

extern "C" void kernel_launch(void* const* d_in, const int* in_sizes, int n_in,
                              void* d_out, int out_size, void* d_ws, size_t ws_size,
                              hipStream_t stream) {
  const float* x  = (const float*)d_in[0];
  const float* Wg = (const float*)d_in[1];
  float* out = (float*)d_out;
  uint4* wt  = (uint4*)d_ws;                       // 256 KB: split-bf16 W planes
  unsigned* ctr  = (unsigned*)d_ws + WT_U4 * 4;    // 1 counter after W planes
  unsigned* list = ctr + 1;                        // token ids to repair
  const int T = in_sizes[0] / D_DIM;               // 65536

  // clamp repair list to available workspace (expected ~900 entries)
  long avail = ((long)ws_size - (long)(WT_U4 * 16 + 4)) / 4;
  int rcap = avail < 0 ? 0 : (avail > 8192 ? 8192 : (int)avail);

  wprep_kernel<<<dim3(NCH * E_DIM * 8 / TPB), dim3(TPB), 0, stream>>>(Wg, wt, ctr);
  router_mfma<<<dim3(T / TM), dim3(TPB), 0, stream>>>(x, wt, out, ctr, list, rcap, T);
  repair_kernel<<<dim3(1024), dim3(256), 0, stream>>>(x, Wg, out, ctr, list, rcap, T);
}